// Round 13
// baseline (232.341 us; speedup 1.0000x reference)
//
#include <hip/hip_runtime.h>
#include <stdint.h>

#define CIN 256
#define PIX 32768
#define MTOT 1152
#define NCOUT 128
#define OHW 129

typedef unsigned short ushort_t;
typedef __attribute__((ext_vector_type(8))) short short8;
typedef __attribute__((ext_vector_type(4))) float f32x4;

__device__ __forceinline__ float b2f(ushort_t u){
  union { unsigned int i; float f; } v; v.i = ((unsigned int)u) << 16; return v.f;
}
__device__ __forceinline__ ushort_t f2b(float f){
  union { float f; unsigned int i; } v; v.f = f;
  unsigned int i = v.i;
  unsigned int r = (i + 0x7FFFu + ((i >> 16) & 1u)) >> 16;
  return (ushort_t)r;
}

// Per-block dtype detect over first 8192 ushorts — COALESCED: thread t reads
// 32 consecutive ushorts (4x uint4), wave shfl-reduce, 1 barrier.
__device__ __forceinline__ int detect_bf16(const ushort_t* __restrict__ p,
                                           float* red, int t){
  const uint4* p4 = (const uint4*)p;
  float mx = 0.f;
#pragma unroll
  for (int j = 0; j < 4; ++j){
    uint4 u = p4[t*4 + j];
    uint w0 = u.x, w1 = u.y, w2 = u.z, w3 = u.w;
#pragma unroll
    for (int e = 0; e < 4; ++e){
      uint w = (e==0)?w0:(e==1)?w1:(e==2)?w2:w3;
      float f0 = fabsf(b2f((ushort_t)(w & 0xffffu)));
      float f1 = fabsf(b2f((ushort_t)(w >> 16)));
      if (!(f0 < 1e30f)) f0 = 1e30f;
      if (!(f1 < 1e30f)) f1 = 1e30f;
      mx = fmaxf(mx, fmaxf(f0, f1));
    }
  }
#pragma unroll
  for (int d = 1; d < 64; d <<= 1) mx = fmaxf(mx, __shfl_xor(mx, d, 64));
  if ((t & 63) == 0) red[t >> 6] = mx;
  __syncthreads();
  float m0 = fmaxf(fmaxf(red[0], red[1]), fmaxf(red[2], red[3]));
  return (m0 < 1e10f);
}

// ------------- Kernel P: fused prep --------------------------------------
// blocks 0..255: x -> xT[pix][ci] (bf16), lam[pix], zero vn2  (block 0 writes flag)
//   bf16 path carries RAW USHORT BITS through the LDS transpose (f2b(b2f(u))==u,
//   so no re-encode needed); f32 decode only feeds the norm accumulation.
// blocks 256..287: z -> PERMUTED zT[n][ci] (coalesced 36-col tiles), A1/B1/S1
__global__ __launch_bounds__(256) void k_prep(const void* __restrict__ xraw,
                                              const void* __restrict__ zraw,
                                              const void* __restrict__ rraw,
                                              ushort_t* __restrict__ xT,
                                              float* __restrict__ lam,
                                              float* __restrict__ vn2,
                                              ushort_t* __restrict__ zT,
                                              float* __restrict__ A1,
                                              float* __restrict__ B1,
                                              float* __restrict__ S1,
                                              float* __restrict__ flag){
  __shared__ float tile[256*37];       // aliased as ushort [64][130] by bf16 path
  __shared__ float ssum[256];
  ushort_t* tileu = (ushort_t*)tile;
  int t = threadIdx.x;
  int bid = blockIdx.x;
  if (bid < 256){
    // ---------------- pixel path (prep_pix) ----------------
    int isb = detect_bf16((const ushort_t*)xraw, ssum, t);
    if (bid == 0 && t == 0) flag[0] = isb ? 1.0f : 0.0f;
    int p0 = bid * 128;
    int b = p0 >> 12;
    int hw0 = p0 & 4095;
    float s = 0.f;
    int p = t & 127, cih = t >> 7;
    for (int ci0 = 0; ci0 < 256; ci0 += 64){
      __syncthreads();
      if (isb){
        // raw-bits tile: [64 ch][130 us] (pad 130 keeps uint alignment, 2-way banks)
        const uint* xb32 = (const uint*)((const ushort_t*)xraw + ((size_t)b*CIN)*4096 + hw0);
#pragma unroll
        for (int i = 0; i < 16; ++i){
          int idx = i*256 + t;          // 0..4095 uint chunks
          int ch = idx >> 6;            // 0..63
          int pp = idx & 63;            // uint column (2 pixels)
          uint u = xb32[(size_t)(ci0+ch)*2048 + pp];
          *(uint*)&tileu[ch*130 + 2*pp] = u;
        }
        __syncthreads();
        // transpose out: 32 raw ushorts (ci) for pixel p; pack pairs, norm from decode
        __align__(8) uint wbuf[16];
#pragma unroll
        for (int j = 0; j < 16; ++j){
          uint b0 = tileu[(cih*32 + 2*j    )*130 + p];
          uint b1 = tileu[(cih*32 + 2*j + 1)*130 + p];
          float f0 = b2f((ushort_t)b0), f1 = b2f((ushort_t)b1);
          s = fmaf(f0, f0, s); s = fmaf(f1, f1, s);
          wbuf[j] = b0 | (b1 << 16);
        }
        uint4* dst = (uint4*)(xT + (size_t)(p0+p)*256 + ci0 + cih*32);
#pragma unroll
        for (int q = 0; q < 4; ++q) dst[q] = *(uint4*)&wbuf[q*4];
      } else {
        const float* xb = (const float*)xraw + ((size_t)b*CIN)*4096 + hw0;
#pragma unroll
        for (int i = 0; i < 32; ++i){
          int idx = i*256 + t;
          int ch = idx >> 7, pp = idx & 127;
          tile[ch*129 + pp] = xb[(size_t)(ci0+ch)*4096 + pp];
        }
        __syncthreads();
        __align__(16) ushort_t buf[32];
#pragma unroll
        for (int i = 0; i < 32; ++i){
          float f = tile[(cih*32+i)*129 + p];
          buf[i] = f2b(f);
          s += f*f;
        }
        uint4* dst = (uint4*)(xT + (size_t)(p0+p)*256 + ci0 + cih*32);
#pragma unroll
        for (int q = 0; q < 4; ++q) dst[q] = *(uint4*)&buf[q*8];
      }
    }
    __syncthreads();
    ssum[t] = s;
    __syncthreads();
    if (t < 128){
      float n2 = ssum[t] + ssum[t+128];
      lam[p0+t] = 2.0f / (1.0f - n2);   // c = 1
      vn2[p0+t] = 0.f;
    }
  } else {
    // ---------------- z path: 32 blocks, 36 consecutive m-columns each -----
    int isb = detect_bf16((const ushort_t*)zraw, ssum, t);
    int zb = bid - 256;                  // 0..31
    int m0 = zb * 36;                    // 36*zb, divisible by 9
    // load tile[ci][mm] = z[ci][m0+mm] (fp32), coalesced: lin = j*256 + t
#pragma unroll
    for (int j = 0; j < 36; ++j){
      int lin = j*256 + t;               // 0..9215
      int ci  = lin / 36;
      int mm  = lin - 36*ci;
      float f;
      if (isb) f = b2f(((const ushort_t*)zraw)[(size_t)ci*MTOT + m0 + mm]);
      else     f = ((const float*)zraw)[(size_t)ci*MTOT + m0 + mm];
      tile[ci*37 + mm] = f;
    }
    __syncthreads();
    // column norms: 4 partials per column (t<144), then combine
    if (t < 144){
      int col = t >> 2, part = t & 3;
      float s = 0.f;
#pragma unroll
      for (int i = 0; i < 64; ++i){
        float f = tile[(part*64 + i)*37 + col];
        s = fmaf(f, f, s);
      }
      ssum[t] = s;
    }
    __syncthreads();
    if (t < 36){
      int m = m0 + t;
      int c = m / 9, k = m - 9*c;
      int n = k*128 + c;
      float zn = fmaxf(sqrtf(ssum[4*t] + ssum[4*t+1] + ssum[4*t+2] + ssum[4*t+3]), 1e-15f);
      float rv = isb ? b2f(((const ushort_t*)rraw)[m]) : ((const float*)rraw)[m];
      float tc = 2.0f * rv;              // tcr = 2*sqrt(c)*r, c=1
      A1[n] = coshf(tc) / zn;
      B1[n] = sinhf(tc);
      S1[n] = 2.0f * zn * 0.69314718055994531f;  // ln2 folded (epilogue uses log2)
    }
    // transposed store: zT[n(j)][ci], coalesced 512B rows
#pragma unroll
    for (int j = 0; j < 36; ++j){
      int m = m0 + j;
      int c = m / 9, k = m - 9*c;
      int n = k*128 + c;
      zT[(size_t)n*256 + t] = f2b(tile[t*37 + j]);
    }
  }
}

// ------------- Kernel 2: swizzled-LDS GEMM + fast-asinh epilogue -------------
// __launch_bounds__(256,4): force <=128 unified regs (64 VGPR + 64 AGPR acc)
// -> 16 waves/CU (was 144 regs -> 8 waves/CU). K-loop live set (~45 VGPR) fits;
// any compiler spill lands in the cold epilogue.
__global__ __launch_bounds__(256, 4) void k_gemm(const ushort_t* __restrict__ xT,
                                              const ushort_t* __restrict__ zT,
                                              const float* __restrict__ lam,
                                              const float* __restrict__ A1,
                                              const float* __restrict__ B1,
                                              const float* __restrict__ S1,
                                              ushort_t* __restrict__ vbuf,
                                              float* __restrict__ vn2,
                                              float* __restrict__ sk){
  __shared__ __align__(16) ushort_t sh[16384];   // As [0,8192), Bs [8192,16384); vtile reuse
  __shared__ float lamS[128], A1S[128], B1S[128], S1S[128];
  int t = threadIdx.x;
  int p0 = blockIdx.x * 128;
  int n0 = blockIdx.y;                 // tap index k; col block = n0*128
  if (t < 128){
    lamS[t] = lam[p0+t];
    A1S[t] = A1[n0*128+t]; B1S[t] = B1[n0*128+t]; S1S[t] = S1[n0*128+t];
  }
  int wave = t >> 6, lane = t & 63;
  int wr = wave >> 1, wc = wave & 1;
  f32x4 acc[4][4];
#pragma unroll
  for (int i=0;i<4;i++)
#pragma unroll
    for (int j=0;j<4;j++) acc[i][j] = (f32x4){0.f,0.f,0.f,0.f};

  for (int kt = 0; kt < 4; ++kt){
    int ci0 = kt*64;
    __syncthreads();
#pragma unroll
    for (int i = 0; i < 4; ++i){
      int sbase = wave*256 + i*64;
      int slot = sbase + lane;
      int row = slot >> 3, jj = slot & 7;
      int j = jj ^ (row & 7);
      const ushort_t* g = xT + (size_t)(p0+row)*256 + ci0 + j*8;
      __builtin_amdgcn_global_load_lds((const __attribute__((address_space(1))) void*)g,
                                       (__attribute__((address_space(3))) void*)&sh[sbase*8],
                                       16, 0, 0);
    }
#pragma unroll
    for (int i = 0; i < 4; ++i){
      int sbase = wave*256 + i*64;
      int slot = sbase + lane;
      int row = slot >> 3, jj = slot & 7;
      int j = jj ^ (row & 7);
      const ushort_t* g = zT + (size_t)(n0*128+row)*256 + ci0 + j*8;
      __builtin_amdgcn_global_load_lds((const __attribute__((address_space(1))) void*)g,
                                       (__attribute__((address_space(3))) void*)&sh[8192 + sbase*8],
                                       16, 0, 0);
    }
    __syncthreads();
#pragma unroll
    for (int ks = 0; ks < 2; ++ks){
      short8 av[4], bv[4];
      int jbase = ks*4 + (lane>>4);
#pragma unroll
      for (int rt = 0; rt < 4; ++rt){
        int row = wr*64 + rt*16 + (lane & 15);
        av[rt] = *(const short8*)&sh[row*64 + ((jbase ^ (row & 7))*8)];
      }
#pragma unroll
      for (int ct = 0; ct < 4; ++ct){
        int mr = wc*64 + ct*16 + (lane & 15);
        bv[ct] = *(const short8*)&sh[8192 + mr*64 + ((jbase ^ (mr & 7))*8)];
      }
#pragma unroll
      for (int rt = 0; rt < 4; ++rt)
#pragma unroll
        for (int ct = 0; ct < 4; ++ct)
          acc[rt][ct] = __builtin_amdgcn_mfma_f32_16x16x32_bf16(av[rt], bv[ct], acc[rt][ct], 0, 0, 0);
    }
  }
  __syncthreads();
  // epilogue: v = S1L * copysign(log2(|tv|+sqrt(tv^2+1)), tv), tv = lam*(xz*A1-B1)+B1
  // (ln2 folded into S1). swizzled vtile (row=16 chunks)
#pragma unroll
  for (int rt = 0; rt < 4; ++rt){
#pragma unroll
    for (int ct = 0; ct < 4; ++ct){
#pragma unroll
      for (int rg = 0; rg < 4; ++rg){
        int row = wr*64 + rt*16 + (lane>>4)*4 + rg;
        int col = wc*64 + ct*16 + (lane & 15);
        float xz = acc[rt][ct][rg];
        float lm = lamS[row];
        float tv = fmaf(lm, fmaf(xz, A1S[col], -B1S[col]), B1S[col]);
        float ax = fabsf(tv);
        float sq = sqrtf(fmaf(ax, ax, 1.0f));
        float lg = __log2f(ax + sq);
        float v = S1S[col] * copysignf(lg, tv);
        sh[row*128 + (((col>>3) ^ (row & 15))*8 + (col & 7))] = f2b(v);
      }
    }
  }
  __syncthreads();
  // pass-2: coalesced vbuf store; v^2 sum computed from the loaded bits
  {
    int row = t >> 1, half = t & 1;
    float s = 0.f;
    uint4* dst = (uint4*)(vbuf + (size_t)(p0+row)*MTOT + n0*128 + half*64);
#pragma unroll
    for (int i = 0; i < 8; ++i){
      int c = half*8 + i;
      uint4 u = *(uint4*)&sh[row*128 + ((c ^ (row & 15))*8)];
      dst[i] = u;
      uint w;
      float f;
      w = u.x; f = b2f((ushort_t)(w & 0xffffu)); s = fmaf(f, f, s);
               f = b2f((ushort_t)(w >> 16));     s = fmaf(f, f, s);
      w = u.y; f = b2f((ushort_t)(w & 0xffffu)); s = fmaf(f, f, s);
               f = b2f((ushort_t)(w >> 16));     s = fmaf(f, f, s);
      w = u.z; f = b2f((ushort_t)(w & 0xffffu)); s = fmaf(f, f, s);
               f = b2f((ushort_t)(w >> 16));     s = fmaf(f, f, s);
      w = u.w; f = b2f((ushort_t)(w & 0xffffu)); s = fmaf(f, f, s);
               f = b2f((ushort_t)(w >> 16));     s = fmaf(f, f, s);
    }
    float s2 = s + __shfl_xor(s, 1, 64);         // combine the two halves
    if (half == 0){
      atomicAdd(&vn2[p0+row], s2);
      sk[(size_t)(p0+row)*9 + n0] = s2;
    }
  }
}

// ------------- Kernel 4: gather fold — 4 same-parity pixels per wave ---------
// block = 512 thr = 8 waves, covers 32 consecutive ox for one (oy, bz).
// wave w: parity q=w&1, group g=w>>1 -> pixels ox = gx*32 + g*8 + q + 2*p,
// p = lane>>4; lane li = lane&15 handles channels 8*li..8*li+7 (uint4 vbuf load).
// ox >= OHW lane-groups skip all loads/math (their stg columns are never read).
__global__ __launch_bounds__(512) void k_fold(const ushort_t* __restrict__ vbuf,
                                              const float* __restrict__ vn2,
                                              const float* __restrict__ sk,
                                              const float* __restrict__ flag,
                                              void* __restrict__ outraw){
  __shared__ ushort_t stg[128*33];     // stg[c*33 + oxl], pad 33 breaks conflicts
  int isb = (flag[0] != 0.0f);
  int t = threadIdx.x;
  int oy = blockIdx.y;
  int bz = blockIdx.z;
  int w = t >> 6, lane = t & 63;
  int p = lane >> 4, li = lane & 15;
  int q = w & 1, g = w >> 1;
  int oxl = g*8 + q + 2*p;             // 0..31, same parity across a wave
  int ox = blockIdx.x*32 + oxl;
  int valid = (ox < OHW);              // uniform within each 16-lane group
  int oxc = min(ox, 128);
  // enumerate contributions with compile-time-bounded unrolled loops (no scratch)
  int khs[2], hs[2], kws[2], wxs[2];
  int ny = 0, nx = 0;
  if (oy & 1){ khs[0]=1; hs[0]=(oy-1)>>1; khs[1]=1; hs[1]=0; ny=1; }
  else {
    khs[0]=0; hs[0]=0; khs[1]=0; hs[1]=0;
    int h0 = oy>>1; if (h0 < 64){ khs[ny]=0; hs[ny]=h0; ny++; }
    if (oy >= 2){ khs[ny]=2; hs[ny]=(oy-2)>>1; ny++; }
  }
  if (oxc & 1){ kws[0]=1; wxs[0]=(oxc-1)>>1; kws[1]=1; wxs[1]=0; nx=1; }
  else {
    kws[0]=0; wxs[0]=0; kws[1]=0; wxs[1]=0;
    int w0 = oxc>>1; if (w0 < 64){ kws[nx]=0; wxs[nx]=w0; nx++; }
    if (oxc >= 2){ kws[nx]=2; wxs[nx]=(oxc-2)>>1; nx++; }
  }
  float num[8];
#pragma unroll
  for (int j = 0; j < 8; ++j) num[j] = 0.f;
  float dacc = 0.f;
  if (valid){
#pragma unroll
    for (int iy = 0; iy < 2; ++iy){
      if (iy < ny){
#pragma unroll
        for (int ix = 0; ix < 2; ++ix){
          if (ix < nx){
            int pix = (bz<<12) + (hs[iy]<<6) + wxs[ix];
            int k = khs[iy]*3 + kws[ix];
            float vn  = vn2[pix];
            float skv = sk[(size_t)pix*9 + k];
            float iv  = 1.0f / (1.0f + sqrtf(1.0f + vn));   // ball map scale
            float l2  = 2.0f / (1.0f - iv*iv*skv);          // conformal factor
            dacc += l2 - 1.0f;
            float scn = l2 * iv;
            uint4 u = *(const uint4*)(vbuf + (size_t)pix*MTOT + k*128 + 8*li);
            uint uu0 = u.x, uu1 = u.y, uu2 = u.z, uu3 = u.w;
            num[0] = fmaf(scn, b2f((ushort_t)(uu0 & 0xffffu)), num[0]);
            num[1] = fmaf(scn, b2f((ushort_t)(uu0 >> 16)),     num[1]);
            num[2] = fmaf(scn, b2f((ushort_t)(uu1 & 0xffffu)), num[2]);
            num[3] = fmaf(scn, b2f((ushort_t)(uu1 >> 16)),     num[3]);
            num[4] = fmaf(scn, b2f((ushort_t)(uu2 & 0xffffu)), num[4]);
            num[5] = fmaf(scn, b2f((ushort_t)(uu2 >> 16)),     num[5]);
            num[6] = fmaf(scn, b2f((ushort_t)(uu3 & 0xffffu)), num[6]);
            num[7] = fmaf(scn, b2f((ushort_t)(uu3 >> 16)),     num[7]);
          }
        }
      }
    }
  }
  float dinv = 1.0f / dacc;
  float fr[8]; float fn2 = 0.f;
#pragma unroll
  for (int j = 0; j < 8; ++j){ fr[j] = num[j]*dinv; fn2 = fmaf(fr[j], fr[j], fn2); }
#pragma unroll
  for (int d = 1; d < 16; d <<= 1) fn2 += __shfl_xor(fn2, d, 64);   // 16-lane group reduce
  float fn = sqrtf(fn2);
  float arg = fminf(fn, 1.0f - 1e-7f);
  // tanh(0.5*atanh(arg)) = arg/(1+sqrt(1-arg^2))
  float scale = arg / ((1.0f + sqrtf(1.0f - arg*arg)) * fmaxf(fn, 1e-15f));
  if (valid){
#pragma unroll
    for (int j = 0; j < 8; ++j) stg[(8*li+j)*33 + oxl] = f2b(fr[j]*scale);
  }
  __syncthreads();
  // writeout: thread -> (c = t>>2, oxg = t&3); 4 threads cover a 64B row chunk
  int c = t >> 2, oxg = t & 3;
#pragma unroll
  for (int i = 0; i < 8; ++i){
    int oxw = blockIdx.x*32 + oxg*8 + i;
    if (oxw < OHW){
      size_t off = (((size_t)bz*NCOUT + c)*OHW + oy)*OHW + oxw;
      ushort_t vv = stg[c*33 + oxg*8 + i];
      if (isb) ((ushort_t*)outraw)[off] = vv;
      else     ((float*)outraw)[off]    = b2f(vv);
    }
  }
}

// ------------- launch --------------------------------------------------------
extern "C" void kernel_launch(void* const* d_in, const int* in_sizes, int n_in,
                              void* d_out, int out_size, void* d_ws, size_t ws_size,
                              hipStream_t stream){
  const void* x = d_in[0];
  const void* z = d_in[1];
  const void* r = d_in[2];
  char* ws = (char*)d_ws;
  size_t off = 0;
  auto alloc = [&](size_t bytes)->char*{ char* p = ws + off; off += (bytes + 255) & ~(size_t)255; return p; };
  ushort_t* xT  = (ushort_t*)alloc((size_t)PIX*CIN*2);
  ushort_t* zT  = (ushort_t*)alloc((size_t)MTOT*CIN*2);
  float* lam    = (float*)alloc((size_t)PIX*4);
  float* vn2    = (float*)alloc((size_t)PIX*4);
  float* A1     = (float*)alloc(MTOT*4);
  float* B1     = (float*)alloc(MTOT*4);
  float* S1     = (float*)alloc(MTOT*4);
  ushort_t* vbuf= (ushort_t*)alloc((size_t)PIX*MTOT*2);
  float* sk     = (float*)alloc((size_t)PIX*9*4);
  float* flag   = (float*)alloc(256);
  (void)in_sizes; (void)n_in; (void)out_size; (void)ws_size;

  hipLaunchKernelGGL(k_prep,  dim3(288),     dim3(256), 0, stream, x, z, r, xT, lam, vn2, zT, A1, B1, S1, flag);
  hipLaunchKernelGGL(k_gemm,  dim3(256,9),   dim3(256), 0, stream, xT, zT, lam, A1, B1, S1, vbuf, vn2, sk);
  hipLaunchKernelGGL(k_fold,  dim3(5,129,8), dim3(512), 0, stream, vbuf, vn2, sk, flag, d_out);
}

// Round 14
// 219.672 us; speedup vs baseline: 1.0577x; 1.0577x over previous
//
#include <hip/hip_runtime.h>
#include <stdint.h>

#define CIN 256
#define PIX 32768
#define MTOT 1152
#define NCOUT 128
#define OHW 129

typedef unsigned short ushort_t;
typedef __attribute__((ext_vector_type(8))) short short8;
typedef __attribute__((ext_vector_type(4))) float f32x4;

__device__ __forceinline__ float b2f(ushort_t u){
  union { unsigned int i; float f; } v; v.i = ((unsigned int)u) << 16; return v.f;
}
__device__ __forceinline__ ushort_t f2b(float f){
  union { float f; unsigned int i; } v; v.f = f;
  unsigned int i = v.i;
  unsigned int r = (i + 0x7FFFu + ((i >> 16) & 1u)) >> 16;
  return (ushort_t)r;
}

// Per-block dtype detect over first 8192 ushorts — COALESCED: thread t reads
// 32 consecutive ushorts (4x uint4), wave shfl-reduce, 1 barrier.
__device__ __forceinline__ int detect_bf16(const ushort_t* __restrict__ p,
                                           float* red, int t){
  const uint4* p4 = (const uint4*)p;
  float mx = 0.f;
#pragma unroll
  for (int j = 0; j < 4; ++j){
    uint4 u = p4[t*4 + j];
    uint w0 = u.x, w1 = u.y, w2 = u.z, w3 = u.w;
#pragma unroll
    for (int e = 0; e < 4; ++e){
      uint w = (e==0)?w0:(e==1)?w1:(e==2)?w2:w3;
      float f0 = fabsf(b2f((ushort_t)(w & 0xffffu)));
      float f1 = fabsf(b2f((ushort_t)(w >> 16)));
      if (!(f0 < 1e30f)) f0 = 1e30f;
      if (!(f1 < 1e30f)) f1 = 1e30f;
      mx = fmaxf(mx, fmaxf(f0, f1));
    }
  }
#pragma unroll
  for (int d = 1; d < 64; d <<= 1) mx = fmaxf(mx, __shfl_xor(mx, d, 64));
  if ((t & 63) == 0) red[t >> 6] = mx;
  __syncthreads();
  float m0 = fmaxf(fmaxf(red[0], red[1]), fmaxf(red[2], red[3]));
  return (m0 < 1e10f);
}

// ------------- Kernel P: fused prep --------------------------------------
// blocks 0..255: x -> xT[pix][ci] (bf16), lam[pix], zero vn2  (block 0 writes flag)
//   bf16 path carries RAW USHORT BITS through the LDS transpose (f2b(b2f(u))==u,
//   so no re-encode needed); f32 decode only feeds the norm accumulation.
// blocks 256..287: z -> PERMUTED zT[n][ci] (coalesced 36-col tiles), A1/B1/S1
__global__ __launch_bounds__(256) void k_prep(const void* __restrict__ xraw,
                                              const void* __restrict__ zraw,
                                              const void* __restrict__ rraw,
                                              ushort_t* __restrict__ xT,
                                              float* __restrict__ lam,
                                              float* __restrict__ vn2,
                                              ushort_t* __restrict__ zT,
                                              float* __restrict__ A1,
                                              float* __restrict__ B1,
                                              float* __restrict__ S1,
                                              float* __restrict__ flag){
  __shared__ float tile[256*37];       // aliased as ushort [64][130] by bf16 path
  __shared__ float ssum[256];
  ushort_t* tileu = (ushort_t*)tile;
  int t = threadIdx.x;
  int bid = blockIdx.x;
  if (bid < 256){
    // ---------------- pixel path (prep_pix) ----------------
    int isb = detect_bf16((const ushort_t*)xraw, ssum, t);
    if (bid == 0 && t == 0) flag[0] = isb ? 1.0f : 0.0f;
    int p0 = bid * 128;
    int b = p0 >> 12;
    int hw0 = p0 & 4095;
    float s = 0.f;
    int p = t & 127, cih = t >> 7;
    for (int ci0 = 0; ci0 < 256; ci0 += 64){
      __syncthreads();
      if (isb){
        // raw-bits tile: [64 ch][130 us] (pad 130 keeps uint alignment, 2-way banks)
        const uint* xb32 = (const uint*)((const ushort_t*)xraw + ((size_t)b*CIN)*4096 + hw0);
#pragma unroll
        for (int i = 0; i < 16; ++i){
          int idx = i*256 + t;          // 0..4095 uint chunks
          int ch = idx >> 6;            // 0..63
          int pp = idx & 63;            // uint column (2 pixels)
          uint u = xb32[(size_t)(ci0+ch)*2048 + pp];
          *(uint*)&tileu[ch*130 + 2*pp] = u;
        }
        __syncthreads();
        // transpose out: 32 raw ushorts (ci) for pixel p; pack pairs, norm from decode
        __align__(8) uint wbuf[16];
#pragma unroll
        for (int j = 0; j < 16; ++j){
          uint b0 = tileu[(cih*32 + 2*j    )*130 + p];
          uint b1 = tileu[(cih*32 + 2*j + 1)*130 + p];
          float f0 = b2f((ushort_t)b0), f1 = b2f((ushort_t)b1);
          s = fmaf(f0, f0, s); s = fmaf(f1, f1, s);
          wbuf[j] = b0 | (b1 << 16);
        }
        uint4* dst = (uint4*)(xT + (size_t)(p0+p)*256 + ci0 + cih*32);
#pragma unroll
        for (int q = 0; q < 4; ++q) dst[q] = *(uint4*)&wbuf[q*4];
      } else {
        const float* xb = (const float*)xraw + ((size_t)b*CIN)*4096 + hw0;
#pragma unroll
        for (int i = 0; i < 32; ++i){
          int idx = i*256 + t;
          int ch = idx >> 7, pp = idx & 127;
          tile[ch*129 + pp] = xb[(size_t)(ci0+ch)*4096 + pp];
        }
        __syncthreads();
        __align__(16) ushort_t buf[32];
#pragma unroll
        for (int i = 0; i < 32; ++i){
          float f = tile[(cih*32+i)*129 + p];
          buf[i] = f2b(f);
          s += f*f;
        }
        uint4* dst = (uint4*)(xT + (size_t)(p0+p)*256 + ci0 + cih*32);
#pragma unroll
        for (int q = 0; q < 4; ++q) dst[q] = *(uint4*)&buf[q*8];
      }
    }
    __syncthreads();
    ssum[t] = s;
    __syncthreads();
    if (t < 128){
      float n2 = ssum[t] + ssum[t+128];
      lam[p0+t] = 2.0f / (1.0f - n2);   // c = 1
      vn2[p0+t] = 0.f;
    }
  } else {
    // ---------------- z path: 32 blocks, 36 consecutive m-columns each -----
    int isb = detect_bf16((const ushort_t*)zraw, ssum, t);
    int zb = bid - 256;                  // 0..31
    int m0 = zb * 36;                    // 36*zb, divisible by 9
    // load tile[ci][mm] = z[ci][m0+mm] (fp32), coalesced: lin = j*256 + t
#pragma unroll
    for (int j = 0; j < 36; ++j){
      int lin = j*256 + t;               // 0..9215
      int ci  = lin / 36;
      int mm  = lin - 36*ci;
      float f;
      if (isb) f = b2f(((const ushort_t*)zraw)[(size_t)ci*MTOT + m0 + mm]);
      else     f = ((const float*)zraw)[(size_t)ci*MTOT + m0 + mm];
      tile[ci*37 + mm] = f;
    }
    __syncthreads();
    // column norms: 4 partials per column (t<144), then combine
    if (t < 144){
      int col = t >> 2, part = t & 3;
      float s = 0.f;
#pragma unroll
      for (int i = 0; i < 64; ++i){
        float f = tile[(part*64 + i)*37 + col];
        s = fmaf(f, f, s);
      }
      ssum[t] = s;
    }
    __syncthreads();
    if (t < 36){
      int m = m0 + t;
      int c = m / 9, k = m - 9*c;
      int n = k*128 + c;
      float zn = fmaxf(sqrtf(ssum[4*t] + ssum[4*t+1] + ssum[4*t+2] + ssum[4*t+3]), 1e-15f);
      float rv = isb ? b2f(((const ushort_t*)rraw)[m]) : ((const float*)rraw)[m];
      float tc = 2.0f * rv;              // tcr = 2*sqrt(c)*r, c=1
      A1[n] = coshf(tc) / zn;
      B1[n] = sinhf(tc);
      S1[n] = 2.0f * zn * 0.69314718055994531f;  // ln2 folded (epilogue uses log2)
    }
    // transposed store: zT[n(j)][ci], coalesced 512B rows
#pragma unroll
    for (int j = 0; j < 36; ++j){
      int m = m0 + j;
      int c = m / 9, k = m - 9*c;
      int n = k*128 + c;
      zT[(size_t)n*256 + t] = f2b(tile[t*37 + j]);
    }
  }
}

// ------------- Kernel 2: swizzled-LDS GEMM + fast-asinh epilogue -------------
// VGPR 80 + 64 AGPR acc = 144 unified -> 3 blocks/CU. Twice-bracketed local
// optimum: register-increasing epilogue rewrites (r4,r7) and register-forcing
// (r13, spills) both regress. Do not restructure.
__global__ __launch_bounds__(256) void k_gemm(const ushort_t* __restrict__ xT,
                                              const ushort_t* __restrict__ zT,
                                              const float* __restrict__ lam,
                                              const float* __restrict__ A1,
                                              const float* __restrict__ B1,
                                              const float* __restrict__ S1,
                                              ushort_t* __restrict__ vbuf,
                                              float* __restrict__ vn2,
                                              float* __restrict__ sk){
  __shared__ __align__(16) ushort_t sh[16384];   // As [0,8192), Bs [8192,16384); vtile reuse
  __shared__ float lamS[128], A1S[128], B1S[128], S1S[128];
  int t = threadIdx.x;
  int p0 = blockIdx.x * 128;
  int n0 = blockIdx.y;                 // tap index k; col block = n0*128
  if (t < 128){
    lamS[t] = lam[p0+t];
    A1S[t] = A1[n0*128+t]; B1S[t] = B1[n0*128+t]; S1S[t] = S1[n0*128+t];
  }
  int wave = t >> 6, lane = t & 63;
  int wr = wave >> 1, wc = wave & 1;
  f32x4 acc[4][4];
#pragma unroll
  for (int i=0;i<4;i++)
#pragma unroll
    for (int j=0;j<4;j++) acc[i][j] = (f32x4){0.f,0.f,0.f,0.f};

  for (int kt = 0; kt < 4; ++kt){
    int ci0 = kt*64;
    __syncthreads();
#pragma unroll
    for (int i = 0; i < 4; ++i){
      int sbase = wave*256 + i*64;
      int slot = sbase + lane;
      int row = slot >> 3, jj = slot & 7;
      int j = jj ^ (row & 7);
      const ushort_t* g = xT + (size_t)(p0+row)*256 + ci0 + j*8;
      __builtin_amdgcn_global_load_lds((const __attribute__((address_space(1))) void*)g,
                                       (__attribute__((address_space(3))) void*)&sh[sbase*8],
                                       16, 0, 0);
    }
#pragma unroll
    for (int i = 0; i < 4; ++i){
      int sbase = wave*256 + i*64;
      int slot = sbase + lane;
      int row = slot >> 3, jj = slot & 7;
      int j = jj ^ (row & 7);
      const ushort_t* g = zT + (size_t)(n0*128+row)*256 + ci0 + j*8;
      __builtin_amdgcn_global_load_lds((const __attribute__((address_space(1))) void*)g,
                                       (__attribute__((address_space(3))) void*)&sh[8192 + sbase*8],
                                       16, 0, 0);
    }
    __syncthreads();
#pragma unroll
    for (int ks = 0; ks < 2; ++ks){
      short8 av[4], bv[4];
      int jbase = ks*4 + (lane>>4);
#pragma unroll
      for (int rt = 0; rt < 4; ++rt){
        int row = wr*64 + rt*16 + (lane & 15);
        av[rt] = *(const short8*)&sh[row*64 + ((jbase ^ (row & 7))*8)];
      }
#pragma unroll
      for (int ct = 0; ct < 4; ++ct){
        int mr = wc*64 + ct*16 + (lane & 15);
        bv[ct] = *(const short8*)&sh[8192 + mr*64 + ((jbase ^ (mr & 7))*8)];
      }
#pragma unroll
      for (int rt = 0; rt < 4; ++rt)
#pragma unroll
        for (int ct = 0; ct < 4; ++ct)
          acc[rt][ct] = __builtin_amdgcn_mfma_f32_16x16x32_bf16(av[rt], bv[ct], acc[rt][ct], 0, 0, 0);
    }
  }
  __syncthreads();
  // epilogue: v = S1L * copysign(log2(|tv|+sqrt(tv^2+1)), tv), tv = lam*(xz*A1-B1)+B1
  // (ln2 folded into S1). swizzled vtile (row=16 chunks)
#pragma unroll
  for (int rt = 0; rt < 4; ++rt){
#pragma unroll
    for (int ct = 0; ct < 4; ++ct){
#pragma unroll
      for (int rg = 0; rg < 4; ++rg){
        int row = wr*64 + rt*16 + (lane>>4)*4 + rg;
        int col = wc*64 + ct*16 + (lane & 15);
        float xz = acc[rt][ct][rg];
        float lm = lamS[row];
        float tv = fmaf(lm, fmaf(xz, A1S[col], -B1S[col]), B1S[col]);
        float ax = fabsf(tv);
        float sq = sqrtf(fmaf(ax, ax, 1.0f));
        float lg = __log2f(ax + sq);
        float v = S1S[col] * copysignf(lg, tv);
        sh[row*128 + (((col>>3) ^ (row & 15))*8 + (col & 7))] = f2b(v);
      }
    }
  }
  __syncthreads();
  // pass-2: coalesced vbuf store; v^2 sum computed from the loaded bits
  {
    int row = t >> 1, half = t & 1;
    float s = 0.f;
    uint4* dst = (uint4*)(vbuf + (size_t)(p0+row)*MTOT + n0*128 + half*64);
#pragma unroll
    for (int i = 0; i < 8; ++i){
      int c = half*8 + i;
      uint4 u = *(uint4*)&sh[row*128 + ((c ^ (row & 15))*8)];
      dst[i] = u;
      uint w;
      float f;
      w = u.x; f = b2f((ushort_t)(w & 0xffffu)); s = fmaf(f, f, s);
               f = b2f((ushort_t)(w >> 16));     s = fmaf(f, f, s);
      w = u.y; f = b2f((ushort_t)(w & 0xffffu)); s = fmaf(f, f, s);
               f = b2f((ushort_t)(w >> 16));     s = fmaf(f, f, s);
      w = u.z; f = b2f((ushort_t)(w & 0xffffu)); s = fmaf(f, f, s);
               f = b2f((ushort_t)(w >> 16));     s = fmaf(f, f, s);
      w = u.w; f = b2f((ushort_t)(w & 0xffffu)); s = fmaf(f, f, s);
               f = b2f((ushort_t)(w >> 16));     s = fmaf(f, f, s);
    }
    float s2 = s + __shfl_xor(s, 1, 64);         // combine the two halves
    if (half == 0){
      atomicAdd(&vn2[p0+row], s2);
      sk[(size_t)(p0+row)*9 + n0] = s2;
    }
  }
}

// ------------- Kernel 4: gather fold — 4 same-parity pixels per wave ---------
// block = 512 thr = 8 waves, covers 32 consecutive ox for one (oy, bz).
// wave w: parity q=w&1, group g=w>>1 -> pixels ox = gx*32 + g*8 + q + 2*p,
// p = lane>>4; lane li = lane&15 handles channels 8*li..8*li+7 (uint4 vbuf load).
// ox >= OHW lane-groups skip all loads/math (their stg columns are never read).
__global__ __launch_bounds__(512) void k_fold(const ushort_t* __restrict__ vbuf,
                                              const float* __restrict__ vn2,
                                              const float* __restrict__ sk,
                                              const float* __restrict__ flag,
                                              void* __restrict__ outraw){
  __shared__ ushort_t stg[128*33];     // stg[c*33 + oxl], pad 33 breaks conflicts
  int isb = (flag[0] != 0.0f);
  int t = threadIdx.x;
  int oy = blockIdx.y;
  int bz = blockIdx.z;
  int w = t >> 6, lane = t & 63;
  int p = lane >> 4, li = lane & 15;
  int q = w & 1, g = w >> 1;
  int oxl = g*8 + q + 2*p;             // 0..31, same parity across a wave
  int ox = blockIdx.x*32 + oxl;
  int valid = (ox < OHW);              // uniform within each 16-lane group
  int oxc = min(ox, 128);
  // enumerate contributions with compile-time-bounded unrolled loops (no scratch)
  int khs[2], hs[2], kws[2], wxs[2];
  int ny = 0, nx = 0;
  if (oy & 1){ khs[0]=1; hs[0]=(oy-1)>>1; khs[1]=1; hs[1]=0; ny=1; }
  else {
    khs[0]=0; hs[0]=0; khs[1]=0; hs[1]=0;
    int h0 = oy>>1; if (h0 < 64){ khs[ny]=0; hs[ny]=h0; ny++; }
    if (oy >= 2){ khs[ny]=2; hs[ny]=(oy-2)>>1; ny++; }
  }
  if (oxc & 1){ kws[0]=1; wxs[0]=(oxc-1)>>1; kws[1]=1; wxs[1]=0; nx=1; }
  else {
    kws[0]=0; wxs[0]=0; kws[1]=0; wxs[1]=0;
    int w0 = oxc>>1; if (w0 < 64){ kws[nx]=0; wxs[nx]=w0; nx++; }
    if (oxc >= 2){ kws[nx]=2; wxs[nx]=(oxc-2)>>1; nx++; }
  }
  float num[8];
#pragma unroll
  for (int j = 0; j < 8; ++j) num[j] = 0.f;
  float dacc = 0.f;
  if (valid){
#pragma unroll
    for (int iy = 0; iy < 2; ++iy){
      if (iy < ny){
#pragma unroll
        for (int ix = 0; ix < 2; ++ix){
          if (ix < nx){
            int pix = (bz<<12) + (hs[iy]<<6) + wxs[ix];
            int k = khs[iy]*3 + kws[ix];
            float vn  = vn2[pix];
            float skv = sk[(size_t)pix*9 + k];
            float iv  = 1.0f / (1.0f + sqrtf(1.0f + vn));   // ball map scale
            float l2  = 2.0f / (1.0f - iv*iv*skv);          // conformal factor
            dacc += l2 - 1.0f;
            float scn = l2 * iv;
            uint4 u = *(const uint4*)(vbuf + (size_t)pix*MTOT + k*128 + 8*li);
            uint uu0 = u.x, uu1 = u.y, uu2 = u.z, uu3 = u.w;
            num[0] = fmaf(scn, b2f((ushort_t)(uu0 & 0xffffu)), num[0]);
            num[1] = fmaf(scn, b2f((ushort_t)(uu0 >> 16)),     num[1]);
            num[2] = fmaf(scn, b2f((ushort_t)(uu1 & 0xffffu)), num[2]);
            num[3] = fmaf(scn, b2f((ushort_t)(uu1 >> 16)),     num[3]);
            num[4] = fmaf(scn, b2f((ushort_t)(uu2 & 0xffffu)), num[4]);
            num[5] = fmaf(scn, b2f((ushort_t)(uu2 >> 16)),     num[5]);
            num[6] = fmaf(scn, b2f((ushort_t)(uu3 & 0xffffu)), num[6]);
            num[7] = fmaf(scn, b2f((ushort_t)(uu3 >> 16)),     num[7]);
          }
        }
      }
    }
  }
  float dinv = 1.0f / dacc;
  float fr[8]; float fn2 = 0.f;
#pragma unroll
  for (int j = 0; j < 8; ++j){ fr[j] = num[j]*dinv; fn2 = fmaf(fr[j], fr[j], fn2); }
#pragma unroll
  for (int d = 1; d < 16; d <<= 1) fn2 += __shfl_xor(fn2, d, 64);   // 16-lane group reduce
  float fn = sqrtf(fn2);
  float arg = fminf(fn, 1.0f - 1e-7f);
  // tanh(0.5*atanh(arg)) = arg/(1+sqrt(1-arg^2))
  float scale = arg / ((1.0f + sqrtf(1.0f - arg*arg)) * fmaxf(fn, 1e-15f));
  if (valid){
#pragma unroll
    for (int j = 0; j < 8; ++j) stg[(8*li+j)*33 + oxl] = f2b(fr[j]*scale);
  }
  __syncthreads();
  // writeout: thread -> (c = t>>2, oxg = t&3); 4 threads cover a 64B row chunk
  int c = t >> 2, oxg = t & 3;
#pragma unroll
  for (int i = 0; i < 8; ++i){
    int oxw = blockIdx.x*32 + oxg*8 + i;
    if (oxw < OHW){
      size_t off = (((size_t)bz*NCOUT + c)*OHW + oy)*OHW + oxw;
      ushort_t vv = stg[c*33 + oxg*8 + i];
      if (isb) ((ushort_t*)outraw)[off] = vv;
      else     ((float*)outraw)[off]    = b2f(vv);
    }
  }
}

// ------------- launch --------------------------------------------------------
extern "C" void kernel_launch(void* const* d_in, const int* in_sizes, int n_in,
                              void* d_out, int out_size, void* d_ws, size_t ws_size,
                              hipStream_t stream){
  const void* x = d_in[0];
  const void* z = d_in[1];
  const void* r = d_in[2];
  char* ws = (char*)d_ws;
  size_t off = 0;
  auto alloc = [&](size_t bytes)->char*{ char* p = ws + off; off += (bytes + 255) & ~(size_t)255; return p; };
  ushort_t* xT  = (ushort_t*)alloc((size_t)PIX*CIN*2);
  ushort_t* zT  = (ushort_t*)alloc((size_t)MTOT*CIN*2);
  float* lam    = (float*)alloc((size_t)PIX*4);
  float* vn2    = (float*)alloc((size_t)PIX*4);
  float* A1     = (float*)alloc(MTOT*4);
  float* B1     = (float*)alloc(MTOT*4);
  float* S1     = (float*)alloc(MTOT*4);
  ushort_t* vbuf= (ushort_t*)alloc((size_t)PIX*MTOT*2);
  float* sk     = (float*)alloc((size_t)PIX*9*4);
  float* flag   = (float*)alloc(256);
  (void)in_sizes; (void)n_in; (void)out_size; (void)ws_size;

  hipLaunchKernelGGL(k_prep,  dim3(288),     dim3(256), 0, stream, x, z, r, xT, lam, vn2, zT, A1, B1, S1, flag);
  hipLaunchKernelGGL(k_gemm,  dim3(256,9),   dim3(256), 0, stream, xT, zT, lam, A1, B1, S1, vbuf, vn2, sk);
  hipLaunchKernelGGL(k_fold,  dim3(5,129,8), dim3(512), 0, stream, vbuf, vn2, sk, flag, d_out);
}